// Round 15
// baseline (151.654 us; speedup 1.0000x reference)
//
#include <hip/hip_runtime.h>
#include <cstdint>

typedef __bf16 bf16x8 __attribute__((ext_vector_type(8)));
typedef float f32x16 __attribute__((ext_vector_type(16)));

#define LOG2E 1.44269504088896340736f

static __device__ __forceinline__ ushort f2bf(float f) {
  uint u = __builtin_bit_cast(uint, f);
  u = u + 0x7FFFu + ((u >> 16) & 1u);   // RNE
  return (ushort)(u >> 16);
}

static __device__ __forceinline__ float bf2f(ushort s) {
  uint u = ((uint)s) << 16;
  return __builtin_bit_cast(float, u);
}

static __device__ __forceinline__ uint cvtpk_bf16(float lo, float hi) {
  uint r;
  asm("v_cvt_pk_bf16_f32 %0, %1, %2" : "=v"(r) : "v"(lo), "v"(hi));
  return r;
}

static __device__ __forceinline__ void plswap(uint& a, uint& b) {
  asm("v_permlane32_swap_b32 %0, %1" : "+v"(a), "+v"(b));
}

// async global->LDS, 16B per lane; LDS dest wave-uniform base + lane*16.
static __device__ __forceinline__ void gload16(const ushort* g, ushort* l) {
  __builtin_amdgcn_global_load_lds(
      (const __attribute__((address_space(1))) void*)g,
      (__attribute__((address_space(3))) void*)l, 16, 0, 0);
}

#if __has_builtin(__builtin_amdgcn_exp2f)
#define EXP2(x) __builtin_amdgcn_exp2f(x)
#else
#define EXP2(x) exp2f(x)
#endif

// ---------------------------------------------------------------------------
// R15: kh DE-FUSION. R10's 8-wave block never exchanges data across its two
// kh-halves inside the loop (pexch/afac/kbuf are kh-partitioned) — the
// per-iter s_barrier over-synchronized 8 waves where 4 suffice. attn_split
// moves kh to the grid: 512 blocks x 4 waves, LDS 58 KB -> 2 independent
// blocks/CU (one group's barrier-skew stalls filled by the other; barrier
// population halved). Partials: kh0 -> out (f32), kh1 -> ws (bf16, rel err
// 0.4% of partial -> ~0.008 abs after merge), merged by a memory-bound
// kernel. Guarded by ws_size (need 38.3 MB); fallback = banked R14 config.
//
// Workspace layouts (all bf16 as ushort):
//   qs2: [b][4096 m][32 d]                      (2 MB)
//   kz : [b][128 T][frag j(2)][lane(64)][i(8)]  (2 MB)
//   vz : [b][128 T][frag j(16)][lane(64)][i(8)] (16 MB)
//   pws: [b][256 c][4096 m] bf16 partial kh1    (16.78 MB)   [split path]
//   mw,lw: [kh][b][4096 m] f32 running max/sum  (2 x 256 KB) [split path]
// A-frag convention (verified R1): lane holds A[row=l31][k=8*hi+i].
// C-layout (m74/m101): col=lane&31, row=(r&3)+8*(r>>2)+4*(lane>>5).
// ---------------------------------------------------------------------------

__global__ __launch_bounds__(256, 2) void proj_qkv(
    const float* __restrict__ x,
    const float* __restrict__ Wq, const float* __restrict__ bq,
    const float* __restrict__ Wk, const float* __restrict__ bk,
    const float* __restrict__ Wv, const float* __restrict__ bv,
    ushort* __restrict__ qo, ushort* __restrict__ ko, ushort* __restrict__ vo)
{
  __shared__ __align__(16) union SM {
    ushort xc[2][8192];        // 32 KB chunk dbuf (A-frag layout, swizzled)
    ushort qT[256 * 40];       // 20 KB q transpose overlay (post-loop)
  } sm;

  const int tid = threadIdx.x;
  const int nt = blockIdx.x, b = blockIdx.y, dt = blockIdx.z;
  const int n0 = nt * 256;
  const int wv = tid >> 6, lane = tid & 63;
  const int l31 = lane & 31, hi = lane >> 5;
  const int dh = wv & 1, nh = wv >> 1;

  // ---- W resident B-frags: lane col = d = l31, k = ci ----
  const float* wrow;
  float wsc = 1.0f;
  if (dt == 0) {
    if (dh == 0) { wrow = Wq + (size_t)l31 * 256; wsc = LOG2E; }
    else         { wrow = Wk + (size_t)l31 * 256; }
  } else {
    wrow = Wv + (size_t)((dt - 1) * 64 + dh * 32 + l31) * 256;
  }
  bf16x8 wf[16];
#pragma unroll
  for (int s = 0; s < 16; ++s) {
    float4 a = *(const float4*)(wrow + s * 16 + 8 * hi);
    float4 c = *(const float4*)(wrow + s * 16 + 8 * hi + 4);
    union { uint u[4]; bf16x8 v; } t;
    t.u[0] = cvtpk_bf16(a.x * wsc, a.y * wsc);
    t.u[1] = cvtpk_bf16(a.z * wsc, a.w * wsc);
    t.u[2] = cvtpk_bf16(c.x * wsc, c.y * wsc);
    t.u[3] = cvtpk_bf16(c.z * wsc, c.w * wsc);
    wf[s] = t.v;
  }

  f32x16 acc[4];
#pragma unroll
  for (int Tl = 0; Tl < 4; ++Tl)
#pragma unroll
    for (int r = 0; r < 16; ++r) acc[Tl][r] = 0.f;

  const float* xb = x + (size_t)b * 256 * 4096;

  // staging role: wave = ci-octet o, lane = n-quad qd
  const int o = wv, qd = lane;
  float4 xr[8];

  auto XLOAD = [&](int kc) {
    const float* src = xb + (size_t)(kc * 32 + 8 * o) * 4096 + n0 + 4 * qd;
#pragma unroll
    for (int j = 0; j < 8; ++j) xr[j] = *(const float4*)(src + (size_t)j * 4096);
  };
  auto XWRITE = [&](int buf) {
    const int base = (qd >> 3) * 1024 + (o >> 1) * 512 + (o & 1) * 256 + (qd & 7) * 32;
    const int xsw = (qd & 6) << 2;
#pragma unroll
    for (int e = 0; e < 4; ++e) {
      uint4 w;
      w.x = cvtpk_bf16(xr[0][e], xr[1][e]);
      w.y = cvtpk_bf16(xr[2][e], xr[3][e]);
      w.z = cvtpk_bf16(xr[4][e], xr[5][e]);
      w.w = cvtpk_bf16(xr[6][e], xr[7][e]);
      *(uint4*)&sm.xc[buf][(base + e * 8) ^ xsw] = w;
    }
  };

  // per-lane A-frag read offset (XOR matches staging swizzle)
  const int rdoff = (lane * 8) ^ (((l31 >> 2) & 6) << 2);

  XLOAD(0);
  asm volatile("s_waitcnt vmcnt(0)" ::: "memory");
  XWRITE(0);
  __syncthreads();

  for (int kc = 0; kc < 8; ++kc) {
    if (kc < 7) XLOAD(kc + 1);
    const ushort* buf = sm.xc[kc & 1];
#pragma unroll
    for (int s2 = 0; s2 < 2; ++s2) {
#pragma unroll
      for (int Tl = 0; Tl < 4; ++Tl) {
        const int T = nh * 4 + Tl;
        bf16x8 a = *(const bf16x8*)&buf[T * 1024 + s2 * 512 + rdoff];
        if (s2 == 0)
          acc[Tl] = __builtin_amdgcn_mfma_f32_32x32x16_bf16(a, wf[kc * 2 + 0], acc[Tl], 0, 0, 0);
        else
          acc[Tl] = __builtin_amdgcn_mfma_f32_32x32x16_bf16(a, wf[kc * 2 + 1], acc[Tl], 0, 0, 0);
      }
    }
    if (kc < 7) {
      asm volatile("s_waitcnt vmcnt(0)" ::: "memory");
      XWRITE((kc + 1) & 1);
    }
    __syncthreads();
  }

  // ---- epilogues ----
  if (dt == 0) {
    if (dh == 0) {
      const float bq_ = bq[l31] * LOG2E;
#pragma unroll
      for (int Tl = 0; Tl < 4; ++Tl)
#pragma unroll
        for (int r = 0; r < 16; ++r) {
          int nl = (nh * 4 + Tl) * 32 + (r & 3) + 8 * (r >> 2) + 4 * hi;
          sm.qT[nl * 40 + l31] = f2bf(acc[Tl][r] + bq_);
        }
    } else {
      const float bk_ = bk[l31];
      const int kd = l31;
      const size_t kzb = (size_t)b * 131072;
      const size_t dbase = (size_t)(kd >> 4) * 512 + ((kd >> 3) & 1) * 256 + (kd & 7);
#pragma unroll
      for (int Tl = 0; Tl < 4; ++Tl) {
        const size_t Tg = (size_t)(nt * 8 + nh * 4 + Tl);
#pragma unroll
        for (int r = 0; r < 16; ++r) {
          int n31 = (r & 3) + 8 * (r >> 2) + 4 * hi;
          ko[kzb + Tg * 1024 + dbase + (size_t)n31 * 8] = f2bf(acc[Tl][r] + bk_);
        }
      }
    }
    __syncthreads();
    {
      ushort* dst = qo + (size_t)b * 131072 + (size_t)(n0 + tid) * 32;
#pragma unroll
      for (int i = 0; i < 4; ++i)
        *(uint4*)(dst + i * 8) = *(const uint4*)&sm.qT[tid * 40 + i * 8];
    }
  } else {
    const float bv_ = bv[(dt - 1) * 64 + dh * 32 + l31];
    const int cu = (dt - 1) * 2 + dh;
    const size_t vzb = (size_t)b * 1048576;
#pragma unroll
    for (int Tl = 0; Tl < 4; ++Tl) {
      const size_t Tg = (size_t)(nt * 8 + nh * 4 + Tl);
#pragma unroll
      for (int g = 0; g < 4; ++g) {
        ushort4 w;
        w.x = f2bf(acc[Tl][g * 4 + 0] + bv_);
        w.y = f2bf(acc[Tl][g * 4 + 1] + bv_);
        w.z = f2bf(acc[Tl][g * 4 + 2] + bv_);
        w.w = f2bf(acc[Tl][g * 4 + 3] + bv_);
        size_t addr = vzb + Tg * 8192 + (size_t)(cu * 2 + (g >> 1)) * 512
                      + (size_t)(g & 1) * 256 + (size_t)l31 * 8 + 4 * hi;
        *(ushort4*)(vo + addr) = w;
      }
    }
  }
}

// ---------------------------------------------------------------------------
// online softmax + P pack only. Returns rescale factor aa (1.0f if deferred).
// ---------------------------------------------------------------------------
static __device__ __forceinline__ float softmax_pack_only(
    f32x16& s, float& mrun, float& lsum, bf16x8& pb0o, bf16x8& pb1o)
{
  float pm = s[0];
#pragma unroll
  for (int r = 1; r < 16; ++r) pm = fmaxf(pm, s[r]);
  pm = fmaxf(pm, __shfl_xor(pm, 32));

  float aa = 1.0f;
  if (!__all(pm <= mrun + 8.0f)) {              // defer-max (T13), log2 domain
    float mnew = fmaxf(mrun, pm);
    aa = EXP2(mrun - mnew);
    mrun = mnew;
    lsum *= aa;
  }

  float p[16];
  float ps = 0.f;
#pragma unroll
  for (int r = 0; r < 16; ++r) { p[r] = EXP2(s[r] - mrun); ps += p[r]; }
  ps += __shfl_xor(ps, 32);
  lsum += ps;

  uint pw[8];
#pragma unroll
  for (int j = 0; j < 8; ++j) pw[j] = cvtpk_bf16(p[2 * j], p[2 * j + 1]);
  plswap(pw[0], pw[2]); plswap(pw[1], pw[3]);
  plswap(pw[4], pw[6]); plswap(pw[5], pw[7]);
  union { uint u[4]; bf16x8 v; } pb0u, pb1u;
  pb0u.u[0] = pw[0]; pb0u.u[1] = pw[1]; pb0u.u[2] = pw[2]; pb0u.u[3] = pw[3];
  pb1u.u[0] = pw[4]; pb1u.u[1] = pw[5]; pb1u.u[2] = pw[6]; pb1u.u[3] = pw[7];
  pb0o = pb0u.v; pb1o = pb1u.v;
  return aa;
}

// ---------------------------------------------------------------------------
// attn_split: R10's loop body verbatim with kh lifted to the grid.
// Block = 256 thr = 4 waves (q = mset & c-quarter), one kh key-half,
// 64 iters. LDS 58 KB -> 2 blocks/CU. Writes UNNORMALIZED partials:
// kh0 -> outp (f32), kh1 -> pws (bf16); per-(kh,m) running (m,l) -> mw/lw.
// ---------------------------------------------------------------------------
__global__ __launch_bounds__(256, 2) void attn_split(
    const ushort* __restrict__ qs, const ushort* __restrict__ kz,
    const ushort* __restrict__ vz, float* __restrict__ outp,
    ushort* __restrict__ pws, float* __restrict__ mw, float* __restrict__ lw)
{
  __shared__ __align__(16) ushort vbuf[4][2][2048];   // 32 KB
  __shared__ __align__(16) ushort kbuf[4][1024];      //  8 KB (4-slot ring)
  __shared__ uint  pexch[2][4][64][8];                // 16 KB
  __shared__ float afac[2][4][64];                    //  2 KB

  const int wg = blockIdx.x;                      // 0..511
  const int swz = (wg & 7) * 64 + (wg >> 3);      // one batch per XCD
  const int b = swz >> 6;
  const int r6 = swz & 63;
  const int kh = r6 >> 5, mt = r6 & 31;
  const int tid = threadIdx.x;
  const int q = tid >> 6, lane = tid & 63;
  const int l31 = lane & 31, hi = lane >> 5;
  const int mbase = mt * 128;
  const int mSelf = mbase + q * 32 + l31;

  // resident Q B-frags for mset q
  const ushort* qrow = qs + (size_t)b * 131072 + (size_t)mSelf * 32;
  bf16x8 qf0 = *(const bf16x8*)(qrow + 8 * hi);
  bf16x8 qf1 = *(const bf16x8*)(qrow + 16 + 8 * hi);

  const ushort* kb = kz + (size_t)b * 131072 + (size_t)kh * 64 * 1024;
  const ushort* vb = vz + (size_t)b * 1048576 + (size_t)kh * 64 * 8192;

  f32x16 acc[4][2];
#pragma unroll
  for (int mu = 0; mu < 4; ++mu)
#pragma unroll
    for (int cf = 0; cf < 2; ++cf)
#pragma unroll
      for (int r = 0; r < 16; ++r) acc[mu][cf][r] = 0.f;

  const f32x16 fzero = {};
  float mrun = -1e30f, lsum = 0.f;

  const int pswz = (lane * 8) ^ (lane & 4);       // pexch XOR swizzle

  auto ISSUE_V = [&](int t, int par) {
#pragma unroll
    for (int i = 0; i < 4; ++i)
      gload16(vb + (size_t)t * 8192 + (size_t)(q * 4 + i) * 512 + lane * 8,
              &vbuf[q][par][i * 512]);
  };
  auto ISSUE_K = [&](int t) {
    if (q < 2)
      gload16(kb + (size_t)t * 1024 + (size_t)q * 512 + lane * 8,
              &kbuf[t & 3][q * 512]);
  };

  // prologue: V(0) K(0) K(1) V(1) K(2)  [q<2: 11 ops, q>=2: 8 ops]
  ISSUE_V(0, 0);
  ISSUE_K(0);
  ISSUE_K(1);
  ISSUE_V(1, 1);
  ISSUE_K(2);
  if (q < 2) { asm volatile("s_waitcnt vmcnt(5)" ::: "memory"); }
  else       { asm volatile("s_waitcnt vmcnt(4)" ::: "memory"); }
  __builtin_amdgcn_s_barrier();   // certifies K(0) for all 4 waves

#define BODY(T, W01, W23)                                                      \
  {                                                                            \
    const int t_ = (T);                                                        \
    const int vpar = t_ & 1, kslot = t_ & 3, xpar = t_ & 1;                    \
    if (q < 2) { asm volatile("s_waitcnt vmcnt(" #W01 ")" ::: "memory"); }     \
    else       { asm volatile("s_waitcnt vmcnt(" #W23 ")" ::: "memory"); }     \
    bf16x8 ka0 = *(const bf16x8*)&kbuf[kslot][lane * 8];                       \
    bf16x8 ka1 = *(const bf16x8*)&kbuf[kslot][512 + lane * 8];                 \
    f32x16 s = __builtin_amdgcn_mfma_f32_32x32x16_bf16(ka0, qf0, fzero, 0, 0, 0); \
    s = __builtin_amdgcn_mfma_f32_32x32x16_bf16(ka1, qf1, s, 0, 0, 0);         \
    bf16x8 pbS0, pbS1;                                                         \
    float aa = softmax_pack_only(s, mrun, lsum, pbS0, pbS1);                   \
    { union { bf16x8 v; uint4 u; } c0, c1; c0.v = pbS0; c1.v = pbS1;           \
      uint* pp = &pexch[xpar][q][0][0];                                        \
      *(uint4*)(pp + pswz) = c0.u;                                             \
      *(uint4*)(pp + (pswz ^ 4)) = c1.u; }                                     \
    afac[xpar][q][lane] = aa;                                                  \
    asm volatile("s_waitcnt lgkmcnt(0)" ::: "memory");                         \
    __builtin_amdgcn_s_barrier();                                              \
    bf16x8 va0 = *(const bf16x8*)&vbuf[q][vpar][0 * 512 + lane * 8];           \
    bf16x8 va1 = *(const bf16x8*)&vbuf[q][vpar][1 * 512 + lane * 8];           \
    bf16x8 va2 = *(const bf16x8*)&vbuf[q][vpar][2 * 512 + lane * 8];           \
    bf16x8 va3 = *(const bf16x8*)&vbuf[q][vpar][3 * 512 + lane * 8];           \
    _Pragma("unroll")                                                          \
    for (int mu = 0; mu < 4; ++mu) {                                           \
      float aaU = afac[xpar][mu][lane];                                        \
      uint* pr = &pexch[xpar][mu][0][0];                                       \
      union { uint4 u; bf16x8 v; } r0, r1;                                     \
      r0.u = *(const uint4*)(pr + pswz);                                       \
      r1.u = *(const uint4*)(pr + (pswz ^ 4));                                 \
      if (!__all(aaU == 1.0f)) {                                               \
        _Pragma("unroll")                                                      \
        for (int cf = 0; cf < 2; ++cf)                                         \
          _Pragma("unroll")                                                    \
          for (int r = 0; r < 16; ++r) acc[mu][cf][r] *= aaU;                  \
      }                                                                        \
      __builtin_amdgcn_s_setprio(1);                                           \
      acc[mu][0] = __builtin_amdgcn_mfma_f32_32x32x16_bf16(va0, r0.v, acc[mu][0], 0, 0, 0); \
      acc[mu][0] = __builtin_amdgcn_mfma_f32_32x32x16_bf16(va1, r1.v, acc[mu][0], 0, 0, 0); \
      acc[mu][1] = __builtin_amdgcn_mfma_f32_32x32x16_bf16(va2, r0.v, acc[mu][1], 0, 0, 0); \
      acc[mu][1] = __builtin_amdgcn_mfma_f32_32x32x16_bf16(va3, r1.v, acc[mu][1], 0, 0, 0); \
      __builtin_amdgcn_s_setprio(0);                                           \
    }                                                                          \
    if (t_ < 62) ISSUE_V(t_ + 2, vpar);                                        \
    if (t_ < 61) ISSUE_K(t_ + 3);                                              \
  }

  for (int t = 0; t < 62; ++t) BODY(t, 5, 4);
  BODY(62, 4, 4);
  BODY(63, 0, 0);
#undef BODY

  // ---- epilogue: write UNNORMALIZED partials + (m,l). No block sync. ----
  if (lane < 32) {
    const size_t mli = ((size_t)kh * 8 + b) * 4096 + mbase + q * 32 + l31;
    mw[mli] = mrun;
    lw[mli] = lsum;
  }
  if (kh == 0) {
    float* op = outp + (size_t)b * 1048576;
#pragma unroll
    for (int mu = 0; mu < 4; ++mu)
#pragma unroll
      for (int cf = 0; cf < 2; ++cf)
#pragma unroll
        for (int r = 0; r < 16; ++r) {
          int c = q * 64 + cf * 32 + (r & 3) + 8 * (r >> 2) + 4 * hi;
          int m = mbase + mu * 32 + l31;
          op[(size_t)c * 4096 + m] = acc[mu][cf][r];
        }
  } else {
    ushort* pp = pws + (size_t)b * 1048576;
#pragma unroll
    for (int mu = 0; mu < 4; ++mu)
#pragma unroll
      for (int cf = 0; cf < 2; ++cf)
#pragma unroll
        for (int r = 0; r < 16; ++r) {
          int c = q * 64 + cf * 32 + (r & 3) + 8 * (r >> 2) + 4 * hi;
          int m = mbase + mu * 32 + l31;
          pp[(size_t)c * 4096 + m] = f2bf(acc[mu][cf][r]);
        }
  }
}

// ---------------------------------------------------------------------------
// merge_split: out = gamma * ((a0*w0 + a1*w1) / (l0*w0 + l1*w1)) + x.
// Memory-bound (~117 MB); float4 grid-stride; ml tables (1 MB) L2-hot.
// Reads out (kh0 partial) and overwrites it in place (per-thread safe).
// ---------------------------------------------------------------------------
__global__ __launch_bounds__(256, 4) void merge_split(
    const ushort* __restrict__ pws, const float* __restrict__ mw,
    const float* __restrict__ lw, const float* __restrict__ x,
    const float* __restrict__ gamma, float* __restrict__ out)
{
  const float g = gamma[0];
  const int nf4 = 8 * 256 * 1024;   // 2,097,152 float4 groups
  for (int i4 = blockIdx.x * 256 + threadIdx.x; i4 < nf4; i4 += gridDim.x * 256) {
    const int m4 = i4 & 1023;
    const int bc = i4 >> 10;
    const int b = bc >> 8;
    const size_t base = (size_t)bc * 4096 + (size_t)m4 * 4;
    float4 a0 = *(const float4*)(out + base);
    ushort4 a1 = *(const ushort4*)(pws + base);
    float4 xv = *(const float4*)(x + base);
    const size_t mb = (size_t)b * 4096 + (size_t)m4 * 4;
    float a0f[4] = {a0.x, a0.y, a0.z, a0.w};
    float a1f[4] = {bf2f(a1.x), bf2f(a1.y), bf2f(a1.z), bf2f(a1.w)};
    float xf[4] = {xv.x, xv.y, xv.z, xv.w};
    float res[4];
#pragma unroll
    for (int j = 0; j < 4; ++j) {
      float m0 = mw[mb + j], m1 = mw[mb + j + 32768];
      float l0 = lw[mb + j], l1 = lw[mb + j + 32768];
      float ms = fmaxf(m0, m1);
      float w0 = EXP2(m0 - ms), w1 = EXP2(m1 - ms);
      float inv = 1.0f / (l0 * w0 + l1 * w1);
      res[j] = g * ((a0f[j] * w0 + a1f[j] * w1) * inv) + xf[j];
    }
    float4 o; o.x = res[0]; o.y = res[1]; o.z = res[2]; o.w = res[3];
    *(float4*)(out + base) = o;
  }
}

// ---------------------------------------------------------------------------
// attn_fused (R10-exact, banked 118.8 us): fallback when ws is too small.
// ---------------------------------------------------------------------------
__global__ __launch_bounds__(512, 2) void attn_fused(
    const ushort* __restrict__ qs, const ushort* __restrict__ kz,
    const ushort* __restrict__ vz, const float* __restrict__ x,
    const float* __restrict__ gamma, float* __restrict__ out)
{
  __shared__ __align__(16) union SMem {
    ushort vbuf[8][2][2048];        // per-wave V c-quarter, dbuf   64 KB
    float  xch[4][2][2][16][64];    // epilogue acc exchange        64 KB
  } sm;
  __shared__ __align__(16) ushort kbuf[2][4][1024];  // K 4-slot ring  16 KB
  __shared__ uint  pexch[2][2][4][64][8];            // packed P       32 KB
  __shared__ float afac[2][2][4][64];                // rescale         4 KB
  __shared__ float mlbuf[2][4][2][64];               // (m,l) final     4 KB

  const int wg = blockIdx.x;                      // 0..255
  const int swz = (wg & 7) * 32 + (wg >> 3);      // one batch per XCD
  const int b = swz >> 5, mt = swz & 31;
  const int tid = threadIdx.x;
  const int wv = tid >> 6, lane = tid & 63;
  const int kh = wv >> 2, q = wv & 3;
  const int l31 = lane & 31, hi = lane >> 5;
  const int mbase = mt * 128;
  const int mSelf = mbase + q * 32 + l31;

  const ushort* qrow = qs + (size_t)b * 131072 + (size_t)mSelf * 32;
  bf16x8 qf0 = *(const bf16x8*)(qrow + 8 * hi);
  bf16x8 qf1 = *(const bf16x8*)(qrow + 16 + 8 * hi);

  const ushort* kb = kz + (size_t)b * 131072 + (size_t)kh * 64 * 1024;
  const ushort* vb = vz + (size_t)b * 1048576 + (size_t)kh * 64 * 8192;

  f32x16 acc[4][2];
#pragma unroll
  for (int mu = 0; mu < 4; ++mu)
#pragma unroll
    for (int cf = 0; cf < 2; ++cf)
#pragma unroll
      for (int r = 0; r < 16; ++r) acc[mu][cf][r] = 0.f;

  const f32x16 fzero = {};
  float mrun = -1e30f, lsum = 0.f;

  const int pswz = (lane * 8) ^ (lane & 4);

  auto ISSUE_V = [&](int t, int par) {
#pragma unroll
    for (int i = 0; i < 4; ++i)
      gload16(vb + (size_t)t * 8192 + (size_t)(q * 4 + i) * 512 + lane * 8,
              &sm.vbuf[wv][par][i * 512]);
  };
  auto ISSUE_K = [&](int t) {
    if (q < 2)
      gload16(kb + (size_t)t * 1024 + (size_t)q * 512 + lane * 8,
              &kbuf[kh][t & 3][q * 512]);
  };

  ISSUE_V(0, 0);
  ISSUE_K(0);
  ISSUE_K(1);
  ISSUE_V(1, 1);
  ISSUE_K(2);
  if (q < 2) { asm volatile("s_waitcnt vmcnt(5)" ::: "memory"); }
  else       { asm volatile("s_waitcnt vmcnt(4)" ::: "memory"); }
  __builtin_amdgcn_s_barrier();

#define BODY(T, W01, W23)                                                      \
  {                                                                            \
    const int t_ = (T);                                                        \
    const int vpar = t_ & 1, kslot = t_ & 3, xpar = t_ & 1;                    \
    if (q < 2) { asm volatile("s_waitcnt vmcnt(" #W01 ")" ::: "memory"); }     \
    else       { asm volatile("s_waitcnt vmcnt(" #W23 ")" ::: "memory"); }     \
    bf16x8 ka0 = *(const bf16x8*)&kbuf[kh][kslot][lane * 8];                   \
    bf16x8 ka1 = *(const bf16x8*)&kbuf[kh][kslot][512 + lane * 8];             \
    f32x16 s = __builtin_amdgcn_mfma_f32_32x32x16_bf16(ka0, qf0, fzero, 0, 0, 0); \
    s = __builtin_amdgcn_mfma_f32_32x32x16_bf16(ka1, qf1, s, 0, 0, 0);         \
    bf16x8 pbS0, pbS1;                                                         \
    float aa = softmax_pack_only(s, mrun, lsum, pbS0, pbS1);                   \
    { union { bf16x8 v; uint4 u; } c0, c1; c0.v = pbS0; c1.v = pbS1;           \
      uint* pp = &pexch[kh][xpar][q][0][0];                                    \
      *(uint4*)(pp + pswz) = c0.u;                                             \
      *(uint4*)(pp + (pswz ^ 4)) = c1.u; }                                     \
    afac[kh][xpar][q][lane] = aa;                                              \
    asm volatile("s_waitcnt lgkmcnt(0)" ::: "memory");                         \
    __builtin_amdgcn_s_barrier();                                              \
    bf16x8 va0 = *(const bf16x8*)&sm.vbuf[wv][vpar][0 * 512 + lane * 8];       \
    bf16x8 va1 = *(const bf16x8*)&sm.vbuf[wv][vpar][1 * 512 + lane * 8];       \
    bf16x8 va2 = *(const bf16x8*)&sm.vbuf[wv][vpar][2 * 512 + lane * 8];       \
    bf16x8 va3 = *(const bf16x8*)&sm.vbuf[wv][vpar][3 * 512 + lane * 8];       \
    _Pragma("unroll")                                                          \
    for (int mu = 0; mu < 4; ++mu) {                                           \
      float aaU = afac[kh][xpar][mu][lane];                                    \
      uint* pr = &pexch[kh][xpar][mu][0][0];                                   \
      union { uint4 u; bf16x8 v; } r0, r1;                                     \
      r0.u = *(const uint4*)(pr + pswz);                                       \
      r1.u = *(const uint4*)(pr + (pswz ^ 4));                                 \
      if (!__all(aaU == 1.0f)) {                                               \
        _Pragma("unroll")                                                      \
        for (int cf = 0; cf < 2; ++cf)                                         \
          _Pragma("unroll")                                                    \
          for (int r = 0; r < 16; ++r) acc[mu][cf][r] *= aaU;                  \
      }                                                                        \
      __builtin_amdgcn_s_setprio(1);                                           \
      acc[mu][0] = __builtin_amdgcn_mfma_f32_32x32x16_bf16(va0, r0.v, acc[mu][0], 0, 0, 0); \
      acc[mu][0] = __builtin_amdgcn_mfma_f32_32x32x16_bf16(va1, r1.v, acc[mu][0], 0, 0, 0); \
      acc[mu][1] = __builtin_amdgcn_mfma_f32_32x32x16_bf16(va2, r0.v, acc[mu][1], 0, 0, 0); \
      acc[mu][1] = __builtin_amdgcn_mfma_f32_32x32x16_bf16(va3, r1.v, acc[mu][1], 0, 0, 0); \
      __builtin_amdgcn_s_setprio(0);                                           \
    }                                                                          \
    if (t_ < 62) ISSUE_V(t_ + 2, vpar);                                        \
    if (t_ < 61) ISSUE_K(t_ + 3);                                              \
  }

  for (int t = 0; t < 62; ++t) BODY(t, 5, 4);
  BODY(62, 4, 4);
  BODY(63, 0, 0);
#undef BODY

  mlbuf[kh][q][0][lane] = mrun;
  mlbuf[kh][q][1][lane] = lsum;
  asm volatile("s_waitcnt lgkmcnt(0)" ::: "memory");
  __builtin_amdgcn_s_barrier();

  const float g = gamma[0];
  const float* xc = x + (size_t)b * 256 * 4096;
  float* oc = out + (size_t)b * 256 * 4096;

  if (kh == 1) {
#pragma unroll
    for (int mu = 0; mu < 2; ++mu)
#pragma unroll
      for (int cf = 0; cf < 2; ++cf)
#pragma unroll
        for (int r = 0; r < 16; ++r)
          sm.xch[q][mu][cf][r][lane] = acc[mu][cf][r];
  }
  asm volatile("s_waitcnt lgkmcnt(0)" ::: "memory");
  __builtin_amdgcn_s_barrier();
  if (kh == 0) {
#pragma unroll
    for (int mu = 0; mu < 2; ++mu) {
      float m0 = mlbuf[0][mu][0][lane], l0 = mlbuf[0][mu][1][lane];
      float m1 = mlbuf[1][mu][0][lane], l1 = mlbuf[1][mu][1][lane];
      float ms = fmaxf(m0, m1);
      float w0 = EXP2(m0 - ms), w1 = EXP2(m1 - ms);
      float inv = 1.0f / (l0 * w0 + l1 * w1);
      int m = mbase + mu * 32 + l31;
#pragma unroll
      for (int cf = 0; cf < 2; ++cf)
#pragma unroll
        for (int r = 0; r < 16; ++r) {
          float val = acc[mu][cf][r] * w0 + sm.xch[q][mu][cf][r][lane] * w1;
          int c = q * 64 + cf * 32 + (r & 3) + 8 * (r >> 2) + 4 * hi;
          oc[(size_t)c * 4096 + m] = g * (val * inv) + xc[(size_t)c * 4096 + m];
        }
    }
  }
  __builtin_amdgcn_s_barrier();
  if (kh == 0) {
#pragma unroll
    for (int mu = 0; mu < 2; ++mu)
#pragma unroll
      for (int cf = 0; cf < 2; ++cf)
#pragma unroll
        for (int r = 0; r < 16; ++r)
          ;  // placeholder keeps structure; kh0 ships nothing in pass B
  } else {
#pragma unroll
    for (int mu = 0; mu < 2; ++mu)
#pragma unroll
      for (int cf = 0; cf < 2; ++cf)
#pragma unroll
        for (int r = 0; r < 16; ++r)
          sm.xch[q][mu][cf][r][lane] = acc[2 + mu][cf][r];
  }
  asm volatile("s_waitcnt lgkmcnt(0)" ::: "memory");
  __builtin_amdgcn_s_barrier();
  if (kh == 0) {
#pragma unroll
    for (int mu = 0; mu < 2; ++mu) {
      float m0 = mlbuf[0][2 + mu][0][lane], l0 = mlbuf[0][2 + mu][1][lane];
      float m1 = mlbuf[1][2 + mu][0][lane], l1 = mlbuf[1][2 + mu][1][lane];
      float ms = fmaxf(m0, m1);
      float w0 = EXP2(m0 - ms), w1 = EXP2(m1 - ms);
      float inv = 1.0f / (l0 * w0 + l1 * w1);
      int m = mbase + (2 + mu) * 32 + l31;
#pragma unroll
      for (int cf = 0; cf < 2; ++cf)
#pragma unroll
        for (int r = 0; r < 16; ++r) {
          float val = acc[2 + mu][cf][r] * w0 + sm.xch[q][mu][cf][r][lane] * w1;
          int c = q * 64 + cf * 32 + (r & 3) + 8 * (r >> 2) + 4 * hi;
          oc[(size_t)c * 4096 + m] = g * (val * inv) + xc[(size_t)c * 4096 + m];
        }
    }
  }
}

extern "C" void kernel_launch(void* const* d_in, const int* in_sizes, int n_in,
                              void* d_out, int out_size, void* d_ws, size_t ws_size,
                              hipStream_t stream) {
  const float* x  = (const float*)d_in[0];
  const float* Wq = (const float*)d_in[1];
  const float* bq = (const float*)d_in[2];
  const float* Wk = (const float*)d_in[3];
  const float* bk = (const float*)d_in[4];
  const float* Wv = (const float*)d_in[5];
  const float* bv = (const float*)d_in[6];
  const float* gm = (const float*)d_in[7];
  float* out = (float*)d_out;

  ushort* qs = (ushort*)d_ws;                       // qs2[m][32d], 2 MB
  ushort* kzp = qs + (size_t)8 * 131072;            // 2 MB
  ushort* vzp = kzp + (size_t)8 * 131072;           // 16 MB

  proj_qkv<<<dim3(16, 8, 5), 256, 0, stream>>>(x, Wq, bq, Wk, bk, Wv, bv, qs, kzp, vzp);

  const size_t NEED = 20971520ull      // qs + kz + vz
                    + 16777216ull      // pws (bf16 kh1 partial)
                    + 262144ull        // mw
                    + 262144ull;       // lw
  if (ws_size >= NEED) {
    ushort* pws = vzp + (size_t)8 * 1048576;
    float* mw = (float*)(pws + (size_t)8 * 1048576);
    float* lw = mw + (size_t)2 * 8 * 4096;
    attn_split<<<dim3(512), 256, 0, stream>>>(qs, kzp, vzp, out, pws, mw, lw);
    merge_split<<<dim3(2048), 256, 0, stream>>>(pws, mw, lw, x, gm, out);
  } else {
    attn_fused<<<dim3(256), 512, 0, stream>>>(qs, kzp, vzp, x, gm, out);
  }
}

// Round 16
// 138.490 us; speedup vs baseline: 1.0951x; 1.0951x over previous
//
#include <hip/hip_runtime.h>
#include <cstdint>

typedef __bf16 bf16x8 __attribute__((ext_vector_type(8)));
typedef float f32x16 __attribute__((ext_vector_type(16)));

#define LOG2E 1.44269504088896340736f

static __device__ __forceinline__ ushort f2bf(float f) {
  uint u = __builtin_bit_cast(uint, f);
  u = u + 0x7FFFu + ((u >> 16) & 1u);   // RNE
  return (ushort)(u >> 16);
}

static __device__ __forceinline__ uint cvtpk_bf16(float lo, float hi) {
  uint r;
  asm("v_cvt_pk_bf16_f32 %0, %1, %2" : "=v"(r) : "v"(lo), "v"(hi));
  return r;
}

static __device__ __forceinline__ void plswap(uint& a, uint& b) {
  asm("v_permlane32_swap_b32 %0, %1" : "+v"(a), "+v"(b));
}

// async global->LDS, 16B per lane; LDS dest wave-uniform base + lane*16.
static __device__ __forceinline__ void gload16(const ushort* g, ushort* l) {
  __builtin_amdgcn_global_load_lds(
      (const __attribute__((address_space(1))) void*)g,
      (__attribute__((address_space(3))) void*)l, 16, 0, 0);
}

#if __has_builtin(__builtin_amdgcn_exp2f)
#define EXP2(x) __builtin_amdgcn_exp2f(x)
#else
#define EXP2(x) exp2f(x)
#endif

// ---------------------------------------------------------------------------
// FINAL BANKED CONFIG (= R10/R14, verified twice at 138.7 us total):
//   proj_qkv  20.7 us — MFMA projections, fragment-major outputs
//   attn_fused 118.0 us — 8-wave all-to-all P-exchange flash attention
// Session post-mortems encoded here:
//   * R11/R12: PV-lagged pipelining raced (V-slot lifetime; ds_read hoisting
//     above raw s_barrier — rule #18 fix is sched_barrier(0) after it).
//   * R13: pipelining + fences correct but SLOWER (130.7) — 2 waves/SIMD
//     already overlap softmax(VALU) with partner PV(MFMA) (m114).
//   * R15: kh de-fusion speeds the loop (107.5) but the cross-block merge
//     costs ~100 MB extra traffic -> net loss (151.7). Reverted.
// Further progress requires a co-designed T16-class schedule, not grafts.
//
// Workspace layouts (all bf16 as ushort):
//   qs2: [b][4096 m][32 d]                      (2 MB)
//   kz : [b][128 T][frag j(2)][lane(64)][i(8)]  (2 MB)
//   vz : [b][128 T][frag j(16)][lane(64)][i(8)] (16 MB)
// A-frag convention (verified R1): lane holds A[row=l31][k=8*hi+i].
// C-layout (m74/m101): col=lane&31, row=(r&3)+8*(r>>2)+4*(lane>>5).
// ---------------------------------------------------------------------------

__global__ __launch_bounds__(256, 2) void proj_qkv(
    const float* __restrict__ x,
    const float* __restrict__ Wq, const float* __restrict__ bq,
    const float* __restrict__ Wk, const float* __restrict__ bk,
    const float* __restrict__ Wv, const float* __restrict__ bv,
    ushort* __restrict__ qo, ushort* __restrict__ ko, ushort* __restrict__ vo)
{
  __shared__ __align__(16) union SM {
    ushort xc[2][8192];        // 32 KB chunk dbuf (A-frag layout, swizzled)
    ushort qT[256 * 40];       // 20 KB q transpose overlay (post-loop)
  } sm;

  const int tid = threadIdx.x;
  const int nt = blockIdx.x, b = blockIdx.y, dt = blockIdx.z;
  const int n0 = nt * 256;
  const int wv = tid >> 6, lane = tid & 63;
  const int l31 = lane & 31, hi = lane >> 5;
  const int dh = wv & 1, nh = wv >> 1;

  // ---- W resident B-frags: lane col = d = l31, k = ci ----
  const float* wrow;
  float wsc = 1.0f;
  if (dt == 0) {
    if (dh == 0) { wrow = Wq + (size_t)l31 * 256; wsc = LOG2E; }
    else         { wrow = Wk + (size_t)l31 * 256; }
  } else {
    wrow = Wv + (size_t)((dt - 1) * 64 + dh * 32 + l31) * 256;
  }
  bf16x8 wf[16];
#pragma unroll
  for (int s = 0; s < 16; ++s) {
    float4 a = *(const float4*)(wrow + s * 16 + 8 * hi);
    float4 c = *(const float4*)(wrow + s * 16 + 8 * hi + 4);
    union { uint u[4]; bf16x8 v; } t;
    t.u[0] = cvtpk_bf16(a.x * wsc, a.y * wsc);
    t.u[1] = cvtpk_bf16(a.z * wsc, a.w * wsc);
    t.u[2] = cvtpk_bf16(c.x * wsc, c.y * wsc);
    t.u[3] = cvtpk_bf16(c.z * wsc, c.w * wsc);
    wf[s] = t.v;
  }

  f32x16 acc[4];
#pragma unroll
  for (int Tl = 0; Tl < 4; ++Tl)
#pragma unroll
    for (int r = 0; r < 16; ++r) acc[Tl][r] = 0.f;

  const float* xb = x + (size_t)b * 256 * 4096;

  // staging role: wave = ci-octet o, lane = n-quad qd
  const int o = wv, qd = lane;
  float4 xr[8];

  auto XLOAD = [&](int kc) {
    const float* src = xb + (size_t)(kc * 32 + 8 * o) * 4096 + n0 + 4 * qd;
#pragma unroll
    for (int j = 0; j < 8; ++j) xr[j] = *(const float4*)(src + (size_t)j * 4096);
  };
  auto XWRITE = [&](int buf) {
    const int base = (qd >> 3) * 1024 + (o >> 1) * 512 + (o & 1) * 256 + (qd & 7) * 32;
    const int xsw = (qd & 6) << 2;
#pragma unroll
    for (int e = 0; e < 4; ++e) {
      uint4 w;
      w.x = cvtpk_bf16(xr[0][e], xr[1][e]);
      w.y = cvtpk_bf16(xr[2][e], xr[3][e]);
      w.z = cvtpk_bf16(xr[4][e], xr[5][e]);
      w.w = cvtpk_bf16(xr[6][e], xr[7][e]);
      *(uint4*)&sm.xc[buf][(base + e * 8) ^ xsw] = w;
    }
  };

  // per-lane A-frag read offset (XOR matches staging swizzle)
  const int rdoff = (lane * 8) ^ (((l31 >> 2) & 6) << 2);

  XLOAD(0);
  asm volatile("s_waitcnt vmcnt(0)" ::: "memory");
  XWRITE(0);
  __syncthreads();

  for (int kc = 0; kc < 8; ++kc) {
    if (kc < 7) XLOAD(kc + 1);
    const ushort* buf = sm.xc[kc & 1];
#pragma unroll
    for (int s2 = 0; s2 < 2; ++s2) {
#pragma unroll
      for (int Tl = 0; Tl < 4; ++Tl) {
        const int T = nh * 4 + Tl;
        bf16x8 a = *(const bf16x8*)&buf[T * 1024 + s2 * 512 + rdoff];
        if (s2 == 0)
          acc[Tl] = __builtin_amdgcn_mfma_f32_32x32x16_bf16(a, wf[kc * 2 + 0], acc[Tl], 0, 0, 0);
        else
          acc[Tl] = __builtin_amdgcn_mfma_f32_32x32x16_bf16(a, wf[kc * 2 + 1], acc[Tl], 0, 0, 0);
      }
    }
    if (kc < 7) {
      asm volatile("s_waitcnt vmcnt(0)" ::: "memory");
      XWRITE((kc + 1) & 1);
    }
    __syncthreads();
  }

  // ---- epilogues ----
  if (dt == 0) {
    if (dh == 0) {
      // q: acc -> LDS transpose (rows padded to 40 ushorts)
      const float bq_ = bq[l31] * LOG2E;
#pragma unroll
      for (int Tl = 0; Tl < 4; ++Tl)
#pragma unroll
        for (int r = 0; r < 16; ++r) {
          int nl = (nh * 4 + Tl) * 32 + (r & 3) + 8 * (r >> 2) + 4 * hi;
          sm.qT[nl * 40 + l31] = f2bf(acc[Tl][r] + bq_);
        }
    } else {
      // k: direct scalar stores into kz
      const float bk_ = bk[l31];
      const int kd = l31;
      const size_t kzb = (size_t)b * 131072;
      const size_t dbase = (size_t)(kd >> 4) * 512 + ((kd >> 3) & 1) * 256 + (kd & 7);
#pragma unroll
      for (int Tl = 0; Tl < 4; ++Tl) {
        const size_t Tg = (size_t)(nt * 8 + nh * 4 + Tl);
#pragma unroll
        for (int r = 0; r < 16; ++r) {
          int n31 = (r & 3) + 8 * (r >> 2) + 4 * hi;
          ko[kzb + Tg * 1024 + dbase + (size_t)n31 * 8] = f2bf(acc[Tl][r] + bk_);
        }
      }
    }
    __syncthreads();
    // all 256 threads: qT -> qs2 coalesced (64B per pixel row)
    {
      ushort* dst = qo + (size_t)b * 131072 + (size_t)(n0 + tid) * 32;
#pragma unroll
      for (int i = 0; i < 4; ++i)
        *(uint4*)(dst + i * 8) = *(const uint4*)&sm.qT[tid * 40 + i * 8];
    }
  } else {
    // v: direct stores into vz (ushort4, 512B-contiguous per wave instr)
    const float bv_ = bv[(dt - 1) * 64 + dh * 32 + l31];
    const int cu = (dt - 1) * 2 + dh;
    const size_t vzb = (size_t)b * 1048576;
#pragma unroll
    for (int Tl = 0; Tl < 4; ++Tl) {
      const size_t Tg = (size_t)(nt * 8 + nh * 4 + Tl);
#pragma unroll
      for (int g = 0; g < 4; ++g) {
        ushort4 w;
        w.x = f2bf(acc[Tl][g * 4 + 0] + bv_);
        w.y = f2bf(acc[Tl][g * 4 + 1] + bv_);
        w.z = f2bf(acc[Tl][g * 4 + 2] + bv_);
        w.w = f2bf(acc[Tl][g * 4 + 3] + bv_);
        size_t addr = vzb + Tg * 8192 + (size_t)(cu * 2 + (g >> 1)) * 512
                      + (size_t)(g & 1) * 256 + (size_t)l31 * 8 + 4 * hi;
        *(ushort4*)(vo + addr) = w;
      }
    }
  }
}

// ---------------------------------------------------------------------------
// online softmax + P pack only. Returns rescale factor aa (1.0f if deferred).
// ---------------------------------------------------------------------------
static __device__ __forceinline__ float softmax_pack_only(
    f32x16& s, float& mrun, float& lsum, bf16x8& pb0o, bf16x8& pb1o)
{
  float pm = s[0];
#pragma unroll
  for (int r = 1; r < 16; ++r) pm = fmaxf(pm, s[r]);
  pm = fmaxf(pm, __shfl_xor(pm, 32));

  float aa = 1.0f;
  if (!__all(pm <= mrun + 8.0f)) {              // defer-max (T13), log2 domain
    float mnew = fmaxf(mrun, pm);
    aa = EXP2(mrun - mnew);
    mrun = mnew;
    lsum *= aa;
  }

  float p[16];
  float ps = 0.f;
#pragma unroll
  for (int r = 0; r < 16; ++r) { p[r] = EXP2(s[r] - mrun); ps += p[r]; }
  ps += __shfl_xor(ps, 32);
  lsum += ps;

  uint pw[8];
#pragma unroll
  for (int j = 0; j < 8; ++j) pw[j] = cvtpk_bf16(p[2 * j], p[2 * j + 1]);
  plswap(pw[0], pw[2]); plswap(pw[1], pw[3]);
  plswap(pw[4], pw[6]); plswap(pw[5], pw[7]);
  union { uint u[4]; bf16x8 v; } pb0u, pb1u;
  pb0u.u[0] = pw[0]; pb0u.u[1] = pw[1]; pb0u.u[2] = pw[2]; pb0u.u[3] = pw[3];
  pb1u.u[0] = pw[4]; pb1u.u[1] = pw[5]; pb1u.u[2] = pw[6]; pb1u.u[3] = pw[7];
  pb0o = pb0u.v; pb1o = pb1u.v;
  return aa;
}

// ---------------------------------------------------------------------------
// attn_fused (R10-exact, 118.0 us): 8-wave all-to-all P-exchange flash
// attention + residual. Block = 512 thr = 8 waves (kh key-half, q = mset &
// c-quarter). Wave (kh,q): softmax mset q over key-half kh; PV ALL 4 msets
// over c-quarter q (acc[4][2] = 128 regs). Packed P + rescale factors
// exchanged all-to-all via double-buffered LDS, ONE raw s_barrier per iter
// (reads placed directly after the barrier — safe without sched fences).
// V private gload_lds 2-deep; K shared per kh, 4-slot ring. 256 blocks =
// 1/CU = 2 waves/SIMD. Cross-kh merge via 64KB LDS overlay, two passes.
// ---------------------------------------------------------------------------
__global__ __launch_bounds__(512, 2) void attn_fused(
    const ushort* __restrict__ qs, const ushort* __restrict__ kz,
    const ushort* __restrict__ vz, const float* __restrict__ x,
    const float* __restrict__ gamma, float* __restrict__ out)
{
  __shared__ __align__(16) union SMem {
    ushort vbuf[8][2][2048];        // per-wave V c-quarter, dbuf   64 KB
    float  xch[4][2][2][16][64];    // epilogue acc exchange        64 KB
  } sm;
  __shared__ __align__(16) ushort kbuf[2][4][1024];  // K 4-slot ring  16 KB
  __shared__ uint  pexch[2][2][4][64][8];            // packed P       32 KB
  __shared__ float afac[2][2][4][64];                // rescale         4 KB
  __shared__ float mlbuf[2][4][2][64];               // (m,l) final     4 KB

  const int wg = blockIdx.x;                      // 0..255
  const int swz = (wg & 7) * 32 + (wg >> 3);      // one batch per XCD
  const int b = swz >> 5, mt = swz & 31;
  const int tid = threadIdx.x;
  const int wv = tid >> 6, lane = tid & 63;
  const int kh = wv >> 2, q = wv & 3;
  const int l31 = lane & 31, hi = lane >> 5;
  const int mbase = mt * 128;
  const int mSelf = mbase + q * 32 + l31;

  // resident Q B-frags for mset q (qs2[m][32d] -> 2 x 16B loads)
  const ushort* qrow = qs + (size_t)b * 131072 + (size_t)mSelf * 32;
  bf16x8 qf0 = *(const bf16x8*)(qrow + 8 * hi);
  bf16x8 qf1 = *(const bf16x8*)(qrow + 16 + 8 * hi);

  const ushort* kb = kz + (size_t)b * 131072 + (size_t)kh * 64 * 1024;
  const ushort* vb = vz + (size_t)b * 1048576 + (size_t)kh * 64 * 8192;

  f32x16 acc[4][2];
#pragma unroll
  for (int mu = 0; mu < 4; ++mu)
#pragma unroll
    for (int cf = 0; cf < 2; ++cf)
#pragma unroll
      for (int r = 0; r < 16; ++r) acc[mu][cf][r] = 0.f;

  const f32x16 fzero = {};
  float mrun = -1e30f, lsum = 0.f;

  const int pswz = (lane * 8) ^ (lane & 4);       // pexch XOR swizzle

  // V: 4 gloads (c-quarter, 4KB) into private vbuf[wv][par]
  auto ISSUE_V = [&](int t, int par) {
#pragma unroll
    for (int i = 0; i < 4; ++i)
      gload16(vb + (size_t)t * 8192 + (size_t)(q * 4 + i) * 512 + lane * 8,
              &sm.vbuf[wv][par][i * 512]);
  };
  // K: waves q=0,1 each stage one 512-ushort frag into the 4-slot ring
  auto ISSUE_K = [&](int t) {
    if (q < 2)
      gload16(kb + (size_t)t * 1024 + (size_t)q * 512 + lane * 8,
              &kbuf[kh][t & 3][q * 512]);
  };

  // prologue: V(0) K(0) K(1) V(1) K(2)  [q<2: 11 ops, q>=2: 8 ops]
  ISSUE_V(0, 0);
  ISSUE_K(0);
  ISSUE_K(1);
  ISSUE_V(1, 1);
  ISSUE_K(2);
  if (q < 2) { asm volatile("s_waitcnt vmcnt(5)" ::: "memory"); }
  else       { asm volatile("s_waitcnt vmcnt(4)" ::: "memory"); }
  __builtin_amdgcn_s_barrier();   // certifies K(0) for all waves

#define BODY(T, W01, W23)                                                      \
  {                                                                            \
    const int t_ = (T);                                                        \
    const int vpar = t_ & 1, kslot = t_ & 3, xpar = t_ & 1;                    \
    if (q < 2) { asm volatile("s_waitcnt vmcnt(" #W01 ")" ::: "memory"); }     \
    else       { asm volatile("s_waitcnt vmcnt(" #W23 ")" ::: "memory"); }     \
    /* QK^T for mset q */                                                      \
    bf16x8 ka0 = *(const bf16x8*)&kbuf[kh][kslot][lane * 8];                   \
    bf16x8 ka1 = *(const bf16x8*)&kbuf[kh][kslot][512 + lane * 8];             \
    f32x16 s = __builtin_amdgcn_mfma_f32_32x32x16_bf16(ka0, qf0, fzero, 0, 0, 0); \
    s = __builtin_amdgcn_mfma_f32_32x32x16_bf16(ka1, qf1, s, 0, 0, 0);         \
    bf16x8 pbS0, pbS1;                                                         \
    float aa = softmax_pack_only(s, mrun, lsum, pbS0, pbS1);                   \
    { union { bf16x8 v; uint4 u; } c0, c1; c0.v = pbS0; c1.v = pbS1;           \
      uint* pp = &pexch[kh][xpar][q][0][0];                                    \
      *(uint4*)(pp + pswz) = c0.u;                                             \
      *(uint4*)(pp + (pswz ^ 4)) = c1.u; }                                     \
    afac[kh][xpar][q][lane] = aa;                                              \
    asm volatile("s_waitcnt lgkmcnt(0)" ::: "memory");                         \
    __builtin_amdgcn_s_barrier();                                              \
    /* V frags once, reused by all 4 msets */                                  \
    bf16x8 va0 = *(const bf16x8*)&sm.vbuf[wv][vpar][0 * 512 + lane * 8];       \
    bf16x8 va1 = *(const bf16x8*)&sm.vbuf[wv][vpar][1 * 512 + lane * 8];       \
    bf16x8 va2 = *(const bf16x8*)&sm.vbuf[wv][vpar][2 * 512 + lane * 8];       \
    bf16x8 va3 = *(const bf16x8*)&sm.vbuf[wv][vpar][3 * 512 + lane * 8];       \
    _Pragma("unroll")                                                          \
    for (int mu = 0; mu < 4; ++mu) {                                           \
      float aaU = afac[kh][xpar][mu][lane];                                    \
      uint* pr = &pexch[kh][xpar][mu][0][0];                                   \
      union { uint4 u; bf16x8 v; } r0, r1;                                     \
      r0.u = *(const uint4*)(pr + pswz);                                       \
      r1.u = *(const uint4*)(pr + (pswz ^ 4));                                 \
      if (!__all(aaU == 1.0f)) {                                               \
        _Pragma("unroll")                                                      \
        for (int cf = 0; cf < 2; ++cf)                                         \
          _Pragma("unroll")                                                    \
          for (int r = 0; r < 16; ++r) acc[mu][cf][r] *= aaU;                  \
      }                                                                        \
      __builtin_amdgcn_s_setprio(1);                                           \
      acc[mu][0] = __builtin_amdgcn_mfma_f32_32x32x16_bf16(va0, r0.v, acc[mu][0], 0, 0, 0); \
      acc[mu][0] = __builtin_amdgcn_mfma_f32_32x32x16_bf16(va1, r1.v, acc[mu][0], 0, 0, 0); \
      acc[mu][1] = __builtin_amdgcn_mfma_f32_32x32x16_bf16(va2, r0.v, acc[mu][1], 0, 0, 0); \
      acc[mu][1] = __builtin_amdgcn_mfma_f32_32x32x16_bf16(va3, r1.v, acc[mu][1], 0, 0, 0); \
      __builtin_amdgcn_s_setprio(0);                                           \
    }                                                                          \
    if (t_ < 62) ISSUE_V(t_ + 2, vpar);                                        \
    if (t_ < 61) ISSUE_K(t_ + 3);                                              \
  }

  for (int t = 0; t < 62; ++t) BODY(t, 5, 4);
  BODY(62, 4, 4);
  BODY(63, 0, 0);
#undef BODY

  // ---- epilogue: cross-kh merge ----
  mlbuf[kh][q][0][lane] = mrun;
  mlbuf[kh][q][1][lane] = lsum;
  asm volatile("s_waitcnt lgkmcnt(0)" ::: "memory");
  __builtin_amdgcn_s_barrier();

  const float g = gamma[0];
  const float* xc = x + (size_t)b * 256 * 4096;
  float* oc = out + (size_t)b * 256 * 4096;

  // pass A: msets 0,1 — kh1 ships, kh0 merges + stores
  if (kh == 1) {
#pragma unroll
    for (int mu = 0; mu < 2; ++mu)
#pragma unroll
      for (int cf = 0; cf < 2; ++cf)
#pragma unroll
        for (int r = 0; r < 16; ++r)
          sm.xch[q][mu][cf][r][lane] = acc[mu][cf][r];
  }
  asm volatile("s_waitcnt lgkmcnt(0)" ::: "memory");
  __builtin_amdgcn_s_barrier();
  if (kh == 0) {
#pragma unroll
    for (int mu = 0; mu < 2; ++mu) {
      float m0 = mlbuf[0][mu][0][lane], l0 = mlbuf[0][mu][1][lane];
      float m1 = mlbuf[1][mu][0][lane], l1 = mlbuf[1][mu][1][lane];
      float ms = fmaxf(m0, m1);
      float w0 = EXP2(m0 - ms), w1 = EXP2(m1 - ms);
      float inv = 1.0f / (l0 * w0 + l1 * w1);
      int m = mbase + mu * 32 + l31;
#pragma unroll
      for (int cf = 0; cf < 2; ++cf)
#pragma unroll
        for (int r = 0; r < 16; ++r) {
          float val = acc[mu][cf][r] * w0 + sm.xch[q][mu][cf][r][lane] * w1;
          int c = q * 64 + cf * 32 + (r & 3) + 8 * (r >> 2) + 4 * hi;
          oc[(size_t)c * 4096 + m] = g * (val * inv) + xc[(size_t)c * 4096 + m];
        }
    }
  }
  __builtin_amdgcn_s_barrier();
  // pass B: msets 2,3
  if (kh == 1) {
#pragma unroll
    for (int mu = 0; mu < 2; ++mu)
#pragma unroll
      for (int cf = 0; cf < 2; ++cf)
#pragma unroll
        for (int r = 0; r < 16; ++r)
          sm.xch[q][mu][cf][r][lane] = acc[2 + mu][cf][r];
  }
  asm volatile("s_waitcnt lgkmcnt(0)" ::: "memory");
  __builtin_amdgcn_s_barrier();
  if (kh == 0) {
#pragma unroll
    for (int mu = 0; mu < 2; ++mu) {
      float m0 = mlbuf[0][2 + mu][0][lane], l0 = mlbuf[0][2 + mu][1][lane];
      float m1 = mlbuf[1][2 + mu][0][lane], l1 = mlbuf[1][2 + mu][1][lane];
      float ms = fmaxf(m0, m1);
      float w0 = EXP2(m0 - ms), w1 = EXP2(m1 - ms);
      float inv = 1.0f / (l0 * w0 + l1 * w1);
      int m = mbase + (2 + mu) * 32 + l31;
#pragma unroll
      for (int cf = 0; cf < 2; ++cf)
#pragma unroll
        for (int r = 0; r < 16; ++r) {
          float val = acc[2 + mu][cf][r] * w0 + sm.xch[q][mu][cf][r][lane] * w1;
          int c = q * 64 + cf * 32 + (r & 3) + 8 * (r >> 2) + 4 * hi;
          oc[(size_t)c * 4096 + m] = g * (val * inv) + xc[(size_t)c * 4096 + m];
        }
    }
  }
}

extern "C" void kernel_launch(void* const* d_in, const int* in_sizes, int n_in,
                              void* d_out, int out_size, void* d_ws, size_t ws_size,
                              hipStream_t stream) {
  const float* x  = (const float*)d_in[0];
  const float* Wq = (const float*)d_in[1];
  const float* bq = (const float*)d_in[2];
  const float* Wk = (const float*)d_in[3];
  const float* bk = (const float*)d_in[4];
  const float* Wv = (const float*)d_in[5];
  const float* bv = (const float*)d_in[6];
  const float* gm = (const float*)d_in[7];
  float* out = (float*)d_out;

  ushort* qs = (ushort*)d_ws;                       // qs2[m][32d], 2 MB
  ushort* kzp = qs + (size_t)8 * 131072;            // 2 MB
  ushort* vzp = kzp + (size_t)8 * 131072;           // 16 MB

  proj_qkv<<<dim3(16, 8, 5), 256, 0, stream>>>(x, Wq, bq, Wk, bk, Wv, bv, qs, kzp, vzp);
  attn_fused<<<dim3(256), 512, 0, stream>>>(qs, kzp, vzp, x, gm, out);
}